// Round 13
// baseline (5933.936 us; speedup 1.0000x reference)
//
#include <hip/hip_runtime.h>
#include <hip/hip_bf16.h>
#include <math.h>

// Problem constants (match reference)
#define V_ 32000
#define D_ 1024
#define E_ 8
#define H_ 4096
#define T_ 2048
#define NHOPS_ 4
#define K_ 2
#define EPS_ 1e-5f

#define LDL 32  // linear LDS row stride (ushorts) for global_load_lds staging (no pad allowed)

typedef __attribute__((ext_vector_type(8))) short short8v;
typedef __attribute__((ext_vector_type(4))) float f32x4;

__device__ __forceinline__ unsigned short f2bf(float f) {
  union { float f; unsigned u; } v;
  v.f = f;
  unsigned r = v.u + 0x7FFF + ((v.u >> 16) & 1);  // RNE
  return (unsigned short)(r >> 16);
}
__device__ __forceinline__ float bf2f(unsigned short b) {
  union { unsigned u; float f; } v;
  v.u = ((unsigned)b) << 16;
  return v.f;
}
// split-bf16: v ~= hi + lo (~2^-17 rel). Expert path must stay near-f32 so
// downstream top-2 routing decisions do not flip vs the f32 reference.
__device__ __forceinline__ void split_bf(float v, unsigned short& hi, unsigned short& lo) {
  hi = f2bf(v);
  lo = f2bf(v - bf2f(hi));
}

__device__ __forceinline__ float gelu_f(float x) {
  float x3 = x * x * x;
  return 0.5f * x * (1.0f + tanhf(0.7978845608028654f * (x + 0.044715f * x3)));
}

// async global->LDS, 16B per lane; LDS dest = wave-uniform base + lane*16
__device__ __forceinline__ void gload_lds16(const void* g, void* l) {
  __builtin_amdgcn_global_load_lds((const __attribute__((address_space(1))) unsigned int*)g,
                                   (__attribute__((address_space(3))) unsigned int*)l, 16, 0, 0);
}

// ------- once-per-launch: split W (f32 [E][R][C]) into transposed bf16 hi/lo [E][C][R] -------
__global__ void k_split_transpose(const float* __restrict__ src, unsigned short* __restrict__ dhi,
                                  unsigned short* __restrict__ dlo, int R, int C) {
  int e = blockIdx.z;
  int r0 = blockIdx.x * 64, c0 = blockIdx.y * 64;
  const float* s = src + (size_t)e * R * C;
  __shared__ float tile[64][65];
  int tid = threadIdx.x;
  int lr = tid >> 6;
  int lc = tid & 63;
#pragma unroll
  for (int p = 0; p < 16; ++p) {
    int rr = p * 4 + lr;
    tile[rr][lc] = s[(size_t)(r0 + rr) * C + c0 + lc];
  }
  __syncthreads();
  unsigned short* ph = dhi + (size_t)e * R * C;
  unsigned short* pl = dlo + (size_t)e * R * C;
#pragma unroll
  for (int p = 0; p < 16; ++p) {
    int cc = p * 4 + lr;
    float v = tile[lc][cc];
    unsigned short hi, lo;
    split_bf(v, hi, lo);
    size_t o = (size_t)(c0 + cc) * R + r0 + lc;
    ph[o] = hi;
    pl[o] = lo;
  }
}

// ------- once-per-launch: embed f32 -> bf16 (same single rounding as before) -------
__global__ void k_prep_emb(const float* __restrict__ embed, unsigned short* __restrict__ embB) {
  int v = blockIdx.x;
  int d = threadIdx.x * 4;
  float4 x = *(const float4*)(embed + (size_t)v * D_ + d);
  unsigned short b4[4];
  b4[0] = f2bf(x.x); b4[1] = f2bf(x.y); b4[2] = f2bf(x.z); b4[3] = f2bf(x.w);
  *(short4*)(embB + (size_t)v * D_ + d) = *(const short4*)b4;
}

// ---------------- gather ----------------
__global__ void k_gather(const int* __restrict__ ids, const float* __restrict__ embed,
                         float* __restrict__ h) {
  int t = blockIdx.x;
  const float4* src = (const float4*)(embed + (size_t)ids[t] * D_);
  float4* dst = (float4*)(h + (size_t)t * D_);
  dst[threadIdx.x] = src[threadIdx.x];
}

// ---------------- router (verified, f32) ----------------
__global__ void k_router(const float* __restrict__ h, const float* __restrict__ rln,
                         const float* __restrict__ rW, float* __restrict__ invr,
                         int* __restrict__ eidx, float* __restrict__ gate) {
  int t = blockIdx.x;
  int tid = threadIdx.x;
  const float* hp = h + (size_t)t * D_;
  float lacc[E_] = {0.f, 0.f, 0.f, 0.f, 0.f, 0.f, 0.f, 0.f};
  float ss = 0.f;
  for (int d = tid; d < D_; d += 256) {
    float x = hp[d];
    ss += x * x;
    float xw = x * rln[d];
    const float* wr = rW + (size_t)d * E_;
#pragma unroll
    for (int e = 0; e < E_; ++e) lacc[e] += xw * wr[e];
  }
  __shared__ float s_l[256][E_];
  __shared__ float s_ss[256];
  __shared__ float s_lg[E_];
  __shared__ float s_ir;
#pragma unroll
  for (int e = 0; e < E_; ++e) s_l[tid][e] = lacc[e];
  s_ss[tid] = ss;
  __syncthreads();
  if (tid < E_) {
    float a = 0.f;
    for (int i = 0; i < 256; ++i) a += s_l[i][tid];
    s_lg[tid] = a;
  } else if (tid == E_) {
    float tot = 0.f;
    for (int i = 0; i < 256; ++i) tot += s_ss[i];
    s_ir = rsqrtf(tot / (float)D_ + EPS_);
  }
  __syncthreads();
  if (tid == 0) {
    float ir = s_ir;
    invr[t] = ir;
    float lg[E_];
#pragma unroll
    for (int e = 0; e < E_; ++e) lg[e] = s_lg[e] * ir;
    int i0 = 0;
#pragma unroll
    for (int e = 1; e < E_; ++e)
      if (lg[e] > lg[i0]) i0 = e;
    int i1 = (i0 == 0) ? 1 : 0;
#pragma unroll
    for (int e = 0; e < E_; ++e)
      if (e != i0 && lg[e] > lg[i1]) i1 = e;
    float m = lg[0];
#pragma unroll
    for (int e = 1; e < E_; ++e) m = fmaxf(m, lg[e]);
    float den = 0.f;
#pragma unroll
    for (int e = 0; e < E_; ++e) den += expf(lg[e] - m);
    eidx[t * 2 + 0] = i0;
    eidx[t * 2 + 1] = i1;
    gate[t * 2 + 0] = expf(lg[i0] - m) / den;
    gate[t * 2 + 1] = expf(lg[i1] - m) / den;
  }
}

// ---------------- grouping (verified; + rowexp) ----------------
__global__ void k_zero_counts(int* counts, int* cursor) {
  if (threadIdx.x < E_) {
    counts[threadIdx.x] = 0;
    cursor[threadIdx.x] = 0;
  }
}
__global__ void k_count(const int* __restrict__ eidx, int* __restrict__ counts) {
  int i = blockIdx.x * 256 + threadIdx.x;
  if (i < T_ * K_) atomicAdd(&counts[eidx[i]], 1);
}
__global__ void k_scan(const int* __restrict__ counts, int* __restrict__ offsets) {
  if (threadIdx.x == 0) {
    int a = 0;
    for (int e = 0; e < E_; ++e) {
      offsets[e] = a;
      a += counts[e];
    }
  }
}
__global__ void k_fill(const int* __restrict__ eidx, const float* __restrict__ gate,
                       const int* __restrict__ offsets, int* __restrict__ cursor,
                       int* __restrict__ rowtok, float* __restrict__ rowgate,
                       int* __restrict__ rowexp) {
  int i = blockIdx.x * 256 + threadIdx.x;
  if (i >= T_ * K_) return;
  int e = eidx[i];
  int p = atomicAdd(&cursor[e], 1);
  int r = offsets[e] + p;
  rowtok[r] = i >> 1;
  rowgate[r] = gate[i];
  rowexp[r] = e;
}

// ------- per-hop: xn[r,:] = split(h[tok]*invr*eln_e) for all T*K rows -------
__global__ void k_prep_xn(const float* __restrict__ h, const float* __restrict__ invr,
                          const float* __restrict__ eln, const int* __restrict__ rowtok,
                          const int* __restrict__ rowexp, unsigned short* __restrict__ xnHi,
                          unsigned short* __restrict__ xnLo) {
  int r = blockIdx.x;
  int tok = rowtok[r];
  int e = rowexp[r];
  float sc = invr[tok];
  int d = threadIdx.x * 4;
  float4 x = *(const float4*)(h + (size_t)tok * D_ + d);
  float4 w = *(const float4*)(eln + (size_t)e * D_ + d);
  unsigned short hi4[4], lo4[4];
  split_bf(x.x * sc * w.x, hi4[0], lo4[0]);
  split_bf(x.y * sc * w.y, hi4[1], lo4[1]);
  split_bf(x.z * sc * w.z, hi4[2], lo4[2]);
  split_bf(x.w * sc * w.w, hi4[3], lo4[3]);
  *(short4*)(xnHi + (size_t)r * D_ + d) = *(const short4*)hi4;
  *(short4*)(xnLo + (size_t)r * D_ + d) = *(const short4*)lo4;
}

// ======= split-bf16 128x128 GEMM core (all operands async-staged) =======
// 4 waves (2x2), each wave owns 64x64 = 4x4 16x16 frags; BK=32; 48 MFMA/wave/K-step.
// A: rows Ksrc from aHi/aLo (row-major, stride AK); B: W T-layout hi/lo (stride BK_).

// ------- gemm1: u = gelu(xn @ W1_e), u stored hi+lo -------
__global__ void k_mfma_gemm1(const unsigned short* __restrict__ xnHi,
                             const unsigned short* __restrict__ xnLo,
                             const unsigned short* __restrict__ W1Thi,
                             const unsigned short* __restrict__ W1Tlo,
                             const int* __restrict__ counts, const int* __restrict__ offsets,
                             unsigned short* __restrict__ uHi, unsigned short* __restrict__ uLo) {
  int e = blockIdx.z;
  int cnt = counts[e];
  int m0 = blockIdx.x * 128;
  if (m0 >= cnt) return;
  int n0 = blockIdx.y * 128;
  int base = offsets[e];

  __shared__ alignas(16) unsigned short Ah[128 * LDL];
  __shared__ alignas(16) unsigned short Al[128 * LDL];
  __shared__ alignas(16) unsigned short Bh[128 * LDL];
  __shared__ alignas(16) unsigned short Bl[128 * LDL];

  int tid = threadIdx.x;
  int lane = tid & 63;
  int wid = tid >> 6;
  int wr = wid >> 1, wc = wid & 1;
  int fr = lane & 15, fs = lane >> 4;

  // staging: wave wid stages rows [wid*32, wid*32+32) of each buffer, 2 insts of 16 rows
  int sr = wid * 32 + (lane >> 2);
  int skq = (lane & 3) * 8;
  int ar0 = base + m0 + sr;
  int ar1 = ar0 + 16;
  if (ar0 >= T_ * K_) ar0 = T_ * K_ - 1;  // tail rows feed discarded outputs only
  if (ar1 >= T_ * K_) ar1 = T_ * K_ - 1;
  const unsigned short* gAh0 = xnHi + (size_t)ar0 * D_ + skq;
  const unsigned short* gAh1 = xnHi + (size_t)ar1 * D_ + skq;
  const unsigned short* gAl0 = xnLo + (size_t)ar0 * D_ + skq;
  const unsigned short* gAl1 = xnLo + (size_t)ar1 * D_ + skq;
  const unsigned short* gBh0 = W1Thi + ((size_t)e * H_ + n0 + sr) * D_ + skq;
  const unsigned short* gBh1 = gBh0 + (size_t)16 * D_;
  const unsigned short* gBl0 = W1Tlo + ((size_t)e * H_ + n0 + sr) * D_ + skq;
  const unsigned short* gBl1 = gBl0 + (size_t)16 * D_;
  unsigned short* lA0 = &Ah[wid * 32 * LDL];
  unsigned short* lA1 = &Ah[(wid * 32 + 16) * LDL];
  unsigned short* lAl0 = &Al[wid * 32 * LDL];
  unsigned short* lAl1 = &Al[(wid * 32 + 16) * LDL];
  unsigned short* lB0 = &Bh[wid * 32 * LDL];
  unsigned short* lB1 = &Bh[(wid * 32 + 16) * LDL];
  unsigned short* lBl0 = &Bl[wid * 32 * LDL];
  unsigned short* lBl1 = &Bl[(wid * 32 + 16) * LDL];

  f32x4 zero4 = {0.f, 0.f, 0.f, 0.f};
  f32x4 acc[4][4];
#pragma unroll
  for (int mi = 0; mi < 4; ++mi)
#pragma unroll
    for (int nj = 0; nj < 4; ++nj) acc[mi][nj] = zero4;

  for (int k0 = 0; k0 < D_; k0 += 32) {
    gload_lds16(gAh0 + k0, lA0);
    gload_lds16(gAh1 + k0, lA1);
    gload_lds16(gAl0 + k0, lAl0);
    gload_lds16(gAl1 + k0, lAl1);
    gload_lds16(gBh0 + k0, lB0);
    gload_lds16(gBh1 + k0, lB1);
    gload_lds16(gBl0 + k0, lBl0);
    gload_lds16(gBl1 + k0, lBl1);
    __syncthreads();
    short8v a_h[4], a_l[4], b_h[4], b_l[4];
#pragma unroll
    for (int mi = 0; mi < 4; ++mi) {
      a_h[mi] = *(const short8v*)&Ah[(wr * 64 + mi * 16 + fr) * LDL + fs * 8];
      a_l[mi] = *(const short8v*)&Al[(wr * 64 + mi * 16 + fr) * LDL + fs * 8];
    }
#pragma unroll
    for (int nj = 0; nj < 4; ++nj) {
      b_h[nj] = *(const short8v*)&Bh[(wc * 64 + nj * 16 + fr) * LDL + fs * 8];
      b_l[nj] = *(const short8v*)&Bl[(wc * 64 + nj * 16 + fr) * LDL + fs * 8];
    }
#pragma unroll
    for (int mi = 0; mi < 4; ++mi)
#pragma unroll
      for (int nj = 0; nj < 4; ++nj) {
        acc[mi][nj] = __builtin_amdgcn_mfma_f32_16x16x32_bf16(a_h[mi], b_h[nj], acc[mi][nj], 0, 0, 0);
        acc[mi][nj] = __builtin_amdgcn_mfma_f32_16x16x32_bf16(a_h[mi], b_l[nj], acc[mi][nj], 0, 0, 0);
        acc[mi][nj] = __builtin_amdgcn_mfma_f32_16x16x32_bf16(a_l[mi], b_h[nj], acc[mi][nj], 0, 0, 0);
      }
    __syncthreads();
  }
#pragma unroll
  for (int mi = 0; mi < 4; ++mi)
#pragma unroll
    for (int i = 0; i < 4; ++i) {
      int row = m0 + wr * 64 + mi * 16 + fs * 4 + i;
      if (row < cnt) {
#pragma unroll
        for (int nj = 0; nj < 4; ++nj) {
          int col = n0 + wc * 64 + nj * 16 + fr;
          float g = gelu_f(acc[mi][nj][i]);
          unsigned short hi, lo;
          split_bf(g, hi, lo);
          size_t idx = (size_t)(base + row) * H_ + col;
          uHi[idx] = hi;
          uLo[idx] = lo;
        }
      }
    }
}

// ------- gemm2: h[tok] += gate * (u @ W2_e) -------
__global__ void k_mfma_gemm2(const unsigned short* __restrict__ uHi,
                             const unsigned short* __restrict__ uLo,
                             const unsigned short* __restrict__ W2Thi,
                             const unsigned short* __restrict__ W2Tlo,
                             const int* __restrict__ counts, const int* __restrict__ offsets,
                             const int* __restrict__ rowtok, const float* __restrict__ rowgate,
                             float* __restrict__ h) {
  int e = blockIdx.z;
  int cnt = counts[e];
  int m0 = blockIdx.x * 128;
  if (m0 >= cnt) return;
  int n0 = blockIdx.y * 128;
  int base = offsets[e];

  __shared__ alignas(16) unsigned short Ah[128 * LDL];
  __shared__ alignas(16) unsigned short Al[128 * LDL];
  __shared__ alignas(16) unsigned short Bh[128 * LDL];
  __shared__ alignas(16) unsigned short Bl[128 * LDL];

  int tid = threadIdx.x;
  int lane = tid & 63;
  int wid = tid >> 6;
  int wr = wid >> 1, wc = wid & 1;
  int fr = lane & 15, fs = lane >> 4;

  int sr = wid * 32 + (lane >> 2);
  int skq = (lane & 3) * 8;
  int ar0 = base + m0 + sr;
  int ar1 = ar0 + 16;
  if (ar0 >= T_ * K_) ar0 = T_ * K_ - 1;
  if (ar1 >= T_ * K_) ar1 = T_ * K_ - 1;
  const unsigned short* gAh0 = uHi + (size_t)ar0 * H_ + skq;
  const unsigned short* gAh1 = uHi + (size_t)ar1 * H_ + skq;
  const unsigned short* gAl0 = uLo + (size_t)ar0 * H_ + skq;
  const unsigned short* gAl1 = uLo + (size_t)ar1 * H_ + skq;
  const unsigned short* gBh0 = W2Thi + ((size_t)e * D_ + n0 + sr) * H_ + skq;
  const unsigned short* gBh1 = gBh0 + (size_t)16 * H_;
  const unsigned short* gBl0 = W2Tlo + ((size_t)e * D_ + n0 + sr) * H_ + skq;
  const unsigned short* gBl1 = gBl0 + (size_t)16 * H_;
  unsigned short* lA0 = &Ah[wid * 32 * LDL];
  unsigned short* lA1 = &Ah[(wid * 32 + 16) * LDL];
  unsigned short* lAl0 = &Al[wid * 32 * LDL];
  unsigned short* lAl1 = &Al[(wid * 32 + 16) * LDL];
  unsigned short* lB0 = &Bh[wid * 32 * LDL];
  unsigned short* lB1 = &Bh[(wid * 32 + 16) * LDL];
  unsigned short* lBl0 = &Bl[wid * 32 * LDL];
  unsigned short* lBl1 = &Bl[(wid * 32 + 16) * LDL];

  f32x4 zero4 = {0.f, 0.f, 0.f, 0.f};
  f32x4 acc[4][4];
#pragma unroll
  for (int mi = 0; mi < 4; ++mi)
#pragma unroll
    for (int nj = 0; nj < 4; ++nj) acc[mi][nj] = zero4;

  for (int k0 = 0; k0 < H_; k0 += 32) {
    gload_lds16(gAh0 + k0, lA0);
    gload_lds16(gAh1 + k0, lA1);
    gload_lds16(gAl0 + k0, lAl0);
    gload_lds16(gAl1 + k0, lAl1);
    gload_lds16(gBh0 + k0, lB0);
    gload_lds16(gBh1 + k0, lB1);
    gload_lds16(gBl0 + k0, lBl0);
    gload_lds16(gBl1 + k0, lBl1);
    __syncthreads();
    short8v a_h[4], a_l[4], b_h[4], b_l[4];
#pragma unroll
    for (int mi = 0; mi < 4; ++mi) {
      a_h[mi] = *(const short8v*)&Ah[(wr * 64 + mi * 16 + fr) * LDL + fs * 8];
      a_l[mi] = *(const short8v*)&Al[(wr * 64 + mi * 16 + fr) * LDL + fs * 8];
    }
#pragma unroll
    for (int nj = 0; nj < 4; ++nj) {
      b_h[nj] = *(const short8v*)&Bh[(wc * 64 + nj * 16 + fr) * LDL + fs * 8];
      b_l[nj] = *(const short8v*)&Bl[(wc * 64 + nj * 16 + fr) * LDL + fs * 8];
    }
#pragma unroll
    for (int mi = 0; mi < 4; ++mi)
#pragma unroll
      for (int nj = 0; nj < 4; ++nj) {
        acc[mi][nj] = __builtin_amdgcn_mfma_f32_16x16x32_bf16(a_h[mi], b_h[nj], acc[mi][nj], 0, 0, 0);
        acc[mi][nj] = __builtin_amdgcn_mfma_f32_16x16x32_bf16(a_h[mi], b_l[nj], acc[mi][nj], 0, 0, 0);
        acc[mi][nj] = __builtin_amdgcn_mfma_f32_16x16x32_bf16(a_l[mi], b_h[nj], acc[mi][nj], 0, 0, 0);
      }
    __syncthreads();
  }
#pragma unroll
  for (int mi = 0; mi < 4; ++mi)
#pragma unroll
    for (int i = 0; i < 4; ++i) {
      int row = m0 + wr * 64 + mi * 16 + fs * 4 + i;
      if (row < cnt) {
        int tok = rowtok[base + row];
        float g = rowgate[base + row];
        float* hp = h + (size_t)tok * D_;
#pragma unroll
        for (int nj = 0; nj < 4; ++nj) {
          int col = n0 + wc * 64 + nj * 16 + fr;
          atomicAdd(&hp[col], g * acc[mi][nj][i]);
        }
      }
    }
}

// ---------------- final rmsnorm -> bf16 ----------------
__global__ void k_finalnorm(const float* __restrict__ h, const float* __restrict__ w,
                            unsigned short* __restrict__ fnb) {
  int t = blockIdx.x;
  int tid = threadIdx.x;
  const float* hp = h + (size_t)t * D_;
  float ss = 0.f;
  for (int d = tid; d < D_; d += 256) {
    float x = hp[d];
    ss += x * x;
  }
  __shared__ float s[256];
  s[tid] = ss;
  __syncthreads();
  for (int o = 128; o > 0; o >>= 1) {
    if (tid < o) s[tid] += s[tid + o];
    __syncthreads();
  }
  float ir = rsqrtf(s[0] / (float)D_ + EPS_);
  for (int d = tid; d < D_; d += 256) fnb[(size_t)t * D_ + d] = f2bf(hp[d] * ir * w[d]);
}

// ------- final GEMM: 128x128, single bf16, both operands async: out = fn . embB^T -------
__global__ void k_mfma_final(const unsigned short* __restrict__ fnb,
                             const unsigned short* __restrict__ embB, float* __restrict__ out) {
  int m0 = blockIdx.x * 128;
  int n0 = blockIdx.y * 128;

  __shared__ alignas(16) unsigned short As[128 * LDL];
  __shared__ alignas(16) unsigned short Bs[128 * LDL];

  int tid = threadIdx.x;
  int lane = tid & 63;
  int wid = tid >> 6;
  int wr = wid >> 1, wc = wid & 1;
  int fr = lane & 15, fs = lane >> 4;

  int sr = wid * 32 + (lane >> 2);
  int skq = (lane & 3) * 8;
  const unsigned short* gA0 = fnb + (size_t)(m0 + sr) * D_ + skq;
  const unsigned short* gA1 = gA0 + (size_t)16 * D_;
  const unsigned short* gB0 = embB + (size_t)(n0 + sr) * D_ + skq;
  const unsigned short* gB1 = gB0 + (size_t)16 * D_;
  unsigned short* lA0 = &As[wid * 32 * LDL];
  unsigned short* lA1 = &As[(wid * 32 + 16) * LDL];
  unsigned short* lB0 = &Bs[wid * 32 * LDL];
  unsigned short* lB1 = &Bs[(wid * 32 + 16) * LDL];

  f32x4 zero4 = {0.f, 0.f, 0.f, 0.f};
  f32x4 acc[4][4];
#pragma unroll
  for (int mi = 0; mi < 4; ++mi)
#pragma unroll
    for (int nj = 0; nj < 4; ++nj) acc[mi][nj] = zero4;

  for (int k0 = 0; k0 < D_; k0 += 32) {
    gload_lds16(gA0 + k0, lA0);
    gload_lds16(gA1 + k0, lA1);
    gload_lds16(gB0 + k0, lB0);
    gload_lds16(gB1 + k0, lB1);
    __syncthreads();
    short8v a_[4], b_[4];
#pragma unroll
    for (int mi = 0; mi < 4; ++mi)
      a_[mi] = *(const short8v*)&As[(wr * 64 + mi * 16 + fr) * LDL + fs * 8];
#pragma unroll
    for (int nj = 0; nj < 4; ++nj)
      b_[nj] = *(const short8v*)&Bs[(wc * 64 + nj * 16 + fr) * LDL + fs * 8];
#pragma unroll
    for (int mi = 0; mi < 4; ++mi)
#pragma unroll
      for (int nj = 0; nj < 4; ++nj)
        acc[mi][nj] = __builtin_amdgcn_mfma_f32_16x16x32_bf16(a_[mi], b_[nj], acc[mi][nj], 0, 0, 0);
    __syncthreads();
  }
#pragma unroll
  for (int mi = 0; mi < 4; ++mi)
#pragma unroll
    for (int i = 0; i < 4; ++i) {
      int row = m0 + wr * 64 + mi * 16 + fs * 4 + i;
      float* op = out + (size_t)row * V_;
#pragma unroll
      for (int nj = 0; nj < 4; ++nj) {
        int col = n0 + wc * 64 + nj * 16 + fr;
        op[col] = acc[mi][nj][i];
      }
    }
}

// ---------------- launch ----------------
extern "C" void kernel_launch(void* const* d_in, const int* in_sizes, int n_in,
                              void* d_out, int out_size, void* d_ws, size_t ws_size,
                              hipStream_t stream) {
  const int* ids = (const int*)d_in[0];
  const float* embed = (const float*)d_in[1];
  const float* router_ln = (const float*)d_in[2];
  const float* router_W = (const float*)d_in[3];
  const float* expert_ln = (const float*)d_in[4];
  const float* W1 = (const float*)d_in[5];
  const float* W2 = (const float*)d_in[6];
  const float* ln_out_w = (const float*)d_in[7];
  float* out = (float*)d_out;

  char* p = (char*)d_ws;
  auto carve = [&](size_t bytes) {
    char* r = p;
    p += (bytes + 255) & ~(size_t)255;
    return (void*)r;
  };
  float* h = (float*)carve((size_t)T_ * D_ * 4);
  unsigned short* fnb = (unsigned short*)carve((size_t)T_ * D_ * 2);
  unsigned short* uHi = (unsigned short*)carve((size_t)T_ * K_ * H_ * 2);
  unsigned short* uLo = (unsigned short*)carve((size_t)T_ * K_ * H_ * 2);
  unsigned short* xnHi = (unsigned short*)carve((size_t)T_ * K_ * D_ * 2);
  unsigned short* xnLo = (unsigned short*)carve((size_t)T_ * K_ * D_ * 2);
  unsigned short* embB = (unsigned short*)carve((size_t)V_ * D_ * 2);
  unsigned short* w1thi = (unsigned short*)carve((size_t)E_ * D_ * H_ * 2);
  unsigned short* w1tlo = (unsigned short*)carve((size_t)E_ * D_ * H_ * 2);
  unsigned short* w2thi = (unsigned short*)carve((size_t)E_ * H_ * D_ * 2);
  unsigned short* w2tlo = (unsigned short*)carve((size_t)E_ * H_ * D_ * 2);
  float* invr = (float*)carve((size_t)T_ * 4);
  int* eidx = (int*)carve((size_t)T_ * K_ * 4);
  float* gate = (float*)carve((size_t)T_ * K_ * 4);
  int* rowtok = (int*)carve((size_t)T_ * K_ * 4);
  float* rowgate = (float*)carve((size_t)T_ * K_ * 4);
  int* rowexp = (int*)carve((size_t)T_ * K_ * 4);
  int* counts = (int*)carve(256);
  int* offsets = (int*)carve(256);
  int* cursor = (int*)carve(256);

  // once per launch: weight split+transpose, embed bf16 conversion
  k_split_transpose<<<dim3(D_ / 64, H_ / 64, E_), 256, 0, stream>>>(W1, w1thi, w1tlo, D_, H_);
  k_split_transpose<<<dim3(H_ / 64, D_ / 64, E_), 256, 0, stream>>>(W2, w2thi, w2tlo, H_, D_);
  k_prep_emb<<<V_, 256, 0, stream>>>(embed, embB);

  k_gather<<<T_, 256, 0, stream>>>(ids, embed, h);

  for (int hop = 0; hop < NHOPS_; ++hop) {
    const float* rln = router_ln + (size_t)hop * D_;
    const float* rW = router_W + (size_t)hop * D_ * E_;
    k_router<<<T_, 256, 0, stream>>>(h, rln, rW, invr, eidx, gate);
    k_zero_counts<<<1, 64, 0, stream>>>(counts, cursor);
    k_count<<<(T_ * K_) / 256, 256, 0, stream>>>(eidx, counts);
    k_scan<<<1, 64, 0, stream>>>(counts, offsets);
    k_fill<<<(T_ * K_) / 256, 256, 0, stream>>>(eidx, gate, offsets, cursor, rowtok, rowgate,
                                                rowexp);
    k_prep_xn<<<T_ * K_, 256, 0, stream>>>(h, invr, expert_ln, rowtok, rowexp, xnHi, xnLo);
    k_mfma_gemm1<<<dim3(T_ * K_ / 128, H_ / 128, E_), 256, 0, stream>>>(
        xnHi, xnLo, w1thi, w1tlo, counts, offsets, uHi, uLo);
    k_mfma_gemm2<<<dim3(T_ * K_ / 128, D_ / 128, E_), 256, 0, stream>>>(
        uHi, uLo, w2thi, w2tlo, counts, offsets, rowtok, rowgate, h);
  }

  k_finalnorm<<<T_, 256, 0, stream>>>(h, ln_out_w, fnb);
  k_mfma_final<<<dim3(T_ / 128, V_ / 128), 256, 0, stream>>>(fnb, embB, out);
}